// Round 1
// baseline (46.083 us; speedup 1.0000x reference)
//
#include <hip/hip_runtime.h>

// Keep IEEE mul-then-add semantics (match JAX/XLA fp32 reference; near-tie
// d0<d1 coset decisions are sensitive to contraction).
#pragma clang fp contract(off)

#define TINY_EPS 1.1920928955078125e-07f  // np.finfo(float32).eps

// D8 closest point, replicating the reference's branchy logic exactly.
// All array indexing is compile-time constant after unrolling (no scratch).
__device__ __forceinline__ void dn8(const float z[8], float out[8]) {
    float f[8], delta[8];
    int par = 0;
#pragma unroll
    for (int j = 0; j < 8; ++j) {
        float x  = z[j];
        float sg = (x > 0.0f) ? 1.0f : ((x < 0.0f) ? -1.0f : 0.0f);
        float fv = floorf((x - sg * TINY_EPS) + 0.5f);  // custom_round
        f[j]     = fv;
        delta[j] = fabsf(x - fv);
        par += (int)fv;  // exact: fv is a small integer-valued float
    }
    // first-max argmax; carry z[k], f[k] along so no runtime indexing
    int   k  = 0;
    float bd = delta[0], xk = z[0], fk = f[0];
#pragma unroll
    for (int j = 1; j < 8; ++j) {
        bool better = delta[j] > bd;  // strict: first max wins (jnp.argmax)
        bd = better ? delta[j] : bd;
        xk = better ? z[j] : xk;
        fk = better ? f[j] : fk;
        k  = better ? j : k;
    }
    // flip direction: x>=0 ? (f<x) : (f<=x)
    bool  up  = (xk >= 0.0f) ? (fk < xk) : (fk <= xk);
    float adj = fk + (up ? 1.0f : -1.0f);
    bool  odd = (par & 1) != 0;
#pragma unroll
    for (int j = 0; j < 8; ++j)
        out[j] = (odd && (j == k)) ? adj : f[j];
}

__global__ void __launch_bounds__(256)
e8_quant_kernel(const float* __restrict__ x, const float* __restrict__ beta_p,
                const float* __restrict__ eps, float* __restrict__ out, int N) {
    int i = blockIdx.x * blockDim.x + threadIdx.x;
    if (i >= N) return;

    float beta = *beta_p;
    float e[8];
#pragma unroll
    for (int j = 0; j < 8; ++j) e[j] = eps[j];  // uniform -> scalar loads / L1 broadcast

    const float4* xp = reinterpret_cast<const float4*>(x) + (size_t)i * 2;
    float4 a = xp[0];
    float4 b = xp[1];
    float  z[8] = {a.x, a.y, a.z, a.w, b.x, b.y, b.z, b.w};
#pragma unroll
    for (int j = 0; j < 8; ++j) z[j] = z[j] / beta + e[j];  // IEEE div (beta==1 -> exact)

    // coset 0: D8(z)
    float y0[8];
    dn8(z, y0);

    // coset 1: D8(z - 0.5) + 0.5
    float zs[8], y1[8];
#pragma unroll
    for (int j = 0; j < 8; ++j) zs[j] = z[j] - 0.5f;
    dn8(zs, y1);
#pragma unroll
    for (int j = 0; j < 8; ++j) y1[j] = y1[j] + 0.5f;

    // squared distances, sequential order j=0..7, explicit round-to-nearest
    // ops (immune to contraction) to bit-match the reference's mul-then-sum.
    float d0 = 0.0f, d1 = 0.0f;
#pragma unroll
    for (int j = 0; j < 8; ++j) {
        float t0 = __fsub_rn(z[j], y0[j]);
        d0       = __fadd_rn(d0, __fmul_rn(t0, t0));
        float t1 = __fsub_rn(z[j], y1[j]);
        d1       = __fadd_rn(d1, __fmul_rn(t1, t1));
    }
    bool pick0 = d0 < d1;  // ties -> y1, matching jnp.where(d0 < d1, y0, y1)

    float q[8];
#pragma unroll
    for (int j = 0; j < 8; ++j) q[j] = beta * (pick0 ? y0[j] : y1[j]);

    float4* op = reinterpret_cast<float4*>(out) + (size_t)i * 2;
    op[0] = make_float4(q[0], q[1], q[2], q[3]);
    op[1] = make_float4(q[4], q[5], q[6], q[7]);
}

extern "C" void kernel_launch(void* const* d_in, const int* in_sizes, int n_in,
                              void* d_out, int out_size, void* d_ws, size_t ws_size,
                              hipStream_t stream) {
    const float* x      = (const float*)d_in[0];
    const float* beta_p = (const float*)d_in[1];
    const float* eps    = (const float*)d_in[2];
    float*       out    = (float*)d_out;

    int N     = in_sizes[0] / 8;  // 4,000,000 points
    int block = 256;
    int grid  = (N + block - 1) / block;
    hipLaunchKernelGGL(e8_quant_kernel, dim3(grid), dim3(block), 0, stream,
                       x, beta_p, eps, out, N);
}